// Round 16
// baseline (213.836 us; speedup 1.0000x reference)
//
#include <hip/hip_runtime.h>

// Problem sizes
#define LN   512      // FFT length
#define FB   257      // rfft bins = L/2+1
#define CB   128      // channels
#define NROW 2048     // B*C rows
#define KF   260      // padded f (65 * 4) for mfma K-loop
#define NP   272      // padded g (17 * 16) — At cols & Zt rows

// LDS bank-despread swizzle for the FFT array (r15, verified)
#define SW(i) ((i) ^ (((i) >> 3) & 7) ^ (((i) >> 6) & 7))

typedef double double4_t __attribute__((ext_vector_type(4)));

// ---------------------------------------------------------------------------
// Kernel 1: blocks [0,1024): paired real FFT (r15 verbatim, swizzled LDS).
// blocks [1024,1577): At_d[f][g] = A[g][f] zero-padded to 260x272.
// blocks [1577,1625): zero xft pad rows f=257..259.
// blocks [1625,3673): gumbel log precompute w01[bi][j] = (-log(u0+1e-20),
//                     -log(u1+1e-20))  (moved out of the mask epilogue).
// ---------------------------------------------------------------------------
__global__ __launch_bounds__(128)
void k_fftprep(const float* __restrict__ x, const float* __restrict__ A,
               const float* __restrict__ gu,
               double* __restrict__ xft, double* __restrict__ At_d,
               double2* __restrict__ w01) {
    const int bx  = blockIdx.x;
    const int tid = threadIdx.x;  // 0..127

    if (bx >= 1024) {
        if (bx < 1577) {                     // At transpose + pad
            int idx = (bx - 1024) * 128 + tid;
            if (idx < KF * NP) {
                int f = idx / NP, g = idx - f * NP;
                At_d[idx] = (f < FB && g < FB) ? (double)A[g * FB + f] : 0.0;
            }
        } else if (bx < 1625) {              // xft pad rows 257..259
            int idx = (bx - 1577) * 128 + tid;   // 48*128 = 6144 = 3*2048
            xft[(size_t)FB * NROW + idx] = 0.0;
        } else {                             // gumbel logs (2048*128 elems)
            int idx = (bx - 1625) * 128 + tid;   // 0 .. 262143
            float2 u2 = ((const float2*)gu)[idx];
            double w0 = -log((double)u2.x + 1e-20);
            double w1 = -log((double)u2.y + 1e-20);
            w01[idx] = make_double2(w0, w1);
        }
        return;
    }

    __shared__ double2 a[LN];
    __shared__ double2 tw[256];
    const int r0 = bx * 2;

    const double PI = 3.14159265358979323846264338327950288;
    for (int t = tid; t < 256; t += 128) {
        double s, c;
        sincos(-2.0 * PI * (double)t / 512.0, &s, &c);
        tw[t] = make_double2(c, s);
    }

    const float* x0 = x + (size_t)r0 * LN;
    const float* x1 = x0 + LN;
    #pragma unroll
    for (int q = 0; q < 4; ++q) {
        int n = tid + 128 * q;
        int r = (int)(__brev((unsigned)n) >> 23);  // 9-bit reverse
        a[SW(r)] = make_double2((double)x0[n], (double)x1[n]);
    }
    __syncthreads();

    #pragma unroll
    for (int s = 1; s <= 7; s += 2) {
        const int h    = 1 << (s - 1);
        const int k    = tid & (h - 1);
        const int grp  = tid >> (s - 1);
        const int base = (grp << (s + 1)) + k;

        double2 a0 = a[SW(base)];
        double2 a1 = a[SW(base + h)];
        double2 a2 = a[SW(base + 2 * h)];
        double2 a3 = a[SW(base + 3 * h)];
        double2 w1  = tw[k << (9 - s)];
        double2 w20 = tw[k << (8 - s)];
        double2 w21 = tw[(k + h) << (8 - s)];

        double vr = a1.x * w1.x - a1.y * w1.y;
        double vi = a1.x * w1.y + a1.y * w1.x;
        double2 t0 = make_double2(a0.x + vr, a0.y + vi);
        double2 t1 = make_double2(a0.x - vr, a0.y - vi);
        vr = a3.x * w1.x - a3.y * w1.y;
        vi = a3.x * w1.y + a3.y * w1.x;
        double2 t2 = make_double2(a2.x + vr, a2.y + vi);
        double2 t3 = make_double2(a2.x - vr, a2.y - vi);

        vr = t2.x * w20.x - t2.y * w20.y;
        vi = t2.x * w20.y + t2.y * w20.x;
        a[SW(base)]         = make_double2(t0.x + vr, t0.y + vi);
        a[SW(base + 2 * h)] = make_double2(t0.x - vr, t0.y - vi);
        vr = t3.x * w21.x - t3.y * w21.y;
        vi = t3.x * w21.y + t3.y * w21.x;
        a[SW(base + h)]     = make_double2(t1.x + vr, t1.y + vi);
        a[SW(base + 3 * h)] = make_double2(t1.x - vr, t1.y - vi);
        __syncthreads();
    }

    #pragma unroll
    for (int u = 0; u < 2; ++u) {
        int t = tid + 128 * u;
        double2 w  = tw[t];
        double2 uu = a[SW(t)];
        double2 v  = a[SW(t + 256)];
        double vr = v.x * w.x - v.y * w.y;
        double vi = v.x * w.y + v.y * w.x;
        a[SW(t)]       = make_double2(uu.x + vr, uu.y + vi);
        a[SW(t + 256)] = make_double2(uu.x - vr, uu.y - vi);
    }
    __syncthreads();

    for (int k = tid; k < FB; k += 128) {
        int m = (LN - k) & (LN - 1);
        double2 zk = a[SW(k)];
        double2 zm = a[SW(m)];
        double xr = 0.5 * (zk.x + zm.x);
        double xi = 0.5 * (zk.y - zm.y);
        double yr = 0.5 * (zk.y + zm.y);
        double yi = 0.5 * (zm.x - zk.x);
        double m0 = sqrt(xr * xr + xi * xi);
        double m1 = sqrt(yr * yr + yi * yi);
        *(double2*)&xft[(size_t)k * NROW + r0] = make_double2(m0, m1);
    }
}

// ---------------------------------------------------------------------------
// Kernel 2 (fused, per-batch): one block per batch, 1024 threads (16 waves).
//   phase 1: zmat — 136 wave-tiles (17 gt x 8 cht), verified MFMA body,
//            Zt[b] written to global (own slab only, no cross-block deps).
//   phase 2: gram — 64 wave-tiles (8 it x 8 jt), verified MFMA body,
//            D written to LDS Gs[128][128] (G global buffer eliminated).
//   phase 3: mask — norms from Gs diagonal; log-free gumbel compare using
//            precomputed w01:  2L >= R  <=>  pr^2*(w1+1e-20) >= (w0+1e-20).
// Workgroup-scope coherence covers the global Zt write->read across the
// internal __syncthreads.
// ---------------------------------------------------------------------------
__global__ __launch_bounds__(1024)
void k_zgm(const double* __restrict__ xft, const double* __restrict__ At_d,
           double* __restrict__ Zt, const double2* __restrict__ w01,
           float* __restrict__ out) {
    extern __shared__ double Gs[];          // [128][128], 128 KB dynamic
    const int b   = blockIdx.x;             // 0..15
    const int tid = threadIdx.x;            // 0..1023
    const int w   = tid >> 6;               // wave 0..15
    const int l   = tid & 63;
    const int q   = l >> 4;                 // k-slot 0..3
    const int m   = l & 15;

    double* Ztb = Zt + (size_t)b * NP * CB;

    // ---- phase 1: zmat (tiles T = w + 16k, T < 136) ----
    for (int T = w; T < 136; T += 16) {
        const int gt   = T % 17;
        const int chtl = T / 17;            // 0..7
        const int g0   = gt * 16;
        const int ch0  = b * CB + chtl * 16;

        const double* pa = At_d + (size_t)q * NP + g0 + m;
        const double* pb = xft + (size_t)q * NROW + ch0 + m;

        double4_t acc = {0.0, 0.0, 0.0, 0.0};
        double a0 = pa[0],              b0 = pb[0];
        double a1 = pa[(size_t)4 * NP], b1 = pb[(size_t)4 * NROW];
        for (int it = 0; it < 63; ++it) {
            double a2 = pa[(size_t)(it + 2) * 4 * NP];
            double b2 = pb[(size_t)(it + 2) * 4 * NROW];
            acc = __builtin_amdgcn_mfma_f64_16x16x4f64(a0, b0, acc, 0, 0, 0);
            a0 = a1; a1 = a2; b0 = b1; b1 = b2;
        }
        acc = __builtin_amdgcn_mfma_f64_16x16x4f64(a0, b0, acc, 0, 0, 0);
        acc = __builtin_amdgcn_mfma_f64_16x16x4f64(a1, b1, acc, 0, 0, 0);

        double* zp = Ztb + (size_t)(g0 + q) * CB + chtl * 16 + m;
        #pragma unroll
        for (int r = 0; r < 4; ++r) zp[(size_t)(4 * r) * CB] = acc[r];
    }
    __syncthreads();

    // ---- phase 2: gram (tiles T2 = w + 16k, T2 < 64) ----
    for (int T2 = w; T2 < 64; T2 += 16) {
        const int it = T2 >> 3;
        const int jt = T2 & 7;
        const int i0 = it * 16, j0 = jt * 16;

        const double* pa = Ztb + (size_t)q * CB + i0 + m;
        const double* pb = Ztb + (size_t)q * CB + j0 + m;

        double4_t acc = {0.0, 0.0, 0.0, 0.0};
        double a0 = pa[0],    b0 = pb[0];
        double a1 = pa[512],  b1 = pb[512];
        double a2 = pa[1024], b2 = pb[1024];
        double a3 = pa[1536], b3 = pb[1536];
        for (int t2 = 0; t2 < 61; ++t2) {
            double an = pa[(size_t)(t2 + 4) * 512];
            double bn = pb[(size_t)(t2 + 4) * 512];
            acc = __builtin_amdgcn_mfma_f64_16x16x4f64(a0, b0, acc, 0, 0, 0);
            a0 = a1; a1 = a2; a2 = a3; a3 = an;
            b0 = b1; b1 = b2; b2 = b3; b3 = bn;
        }
        acc = __builtin_amdgcn_mfma_f64_16x16x4f64(a0, b0, acc, 0, 0, 0);
        acc = __builtin_amdgcn_mfma_f64_16x16x4f64(a1, b1, acc, 0, 0, 0);
        acc = __builtin_amdgcn_mfma_f64_16x16x4f64(a2, b2, acc, 0, 0, 0);
        acc = __builtin_amdgcn_mfma_f64_16x16x4f64(a3, b3, acc, 0, 0, 0);

        // D row = q + 4*reg (verified mapping), store into LDS
        #pragma unroll
        for (int r = 0; r < 4; ++r)
            Gs[(size_t)(i0 + q + 4 * r) * CB + j0 + m] = acc[r];
    }
    __syncthreads();

    // ---- phase 3: mask.  wave w handles rows i = w*8 + rep ----
    for (int rep = 0; rep < 8; ++rep) {
        const int i  = w * 8 + rep;          // 0..127
        const int bi = b * CB + i;

        double ni  = Gs[(size_t)i * CB + i];
        double nj0 = Gs[(size_t)l * CB + l];
        double nj1 = Gs[(size_t)(l + 64) * CB + (l + 64)];
        double Gv0 = Gs[(size_t)i * CB + l];
        double Gv1 = Gs[(size_t)i * CB + l + 64];

        double d0 = ni + nj0 - 2.0 * Gv0;
        double d1 = ni + nj1 - 2.0 * Gv1;
        double e0 = 1.0 / (d0 + 3e-8);
        double e1 = 1.0 / (d1 + 3e-8);
        if (l == i)      e0 = 0.0;           // * (1 - eye)
        if (l + 64 == i) e1 = 0.0;

        double mx = fmax(e0, e1);
        #pragma unroll
        for (int off = 32; off >= 1; off >>= 1)
            mx = fmax(mx, __shfl_xor(mx, off, 64));
        double emax = mx + 1e-8;

        double p0 = e0 / emax;
        double p1 = e1 / emax;
        if (l == i)      p0 += 1.0;          // + eye
        if (l + 64 == i) p1 += 1.0;
        p0 *= 0.99;
        p1 *= 0.99;
        double pr0 = (p0 + 1e-8) / (1.0 - p0 + 1e-8);
        double pr1 = (p1 + 1e-8) / (1.0 - p1 + 1e-8);

        double2 wv0 = w01[(size_t)bi * CB + l];
        double2 wv1 = w01[(size_t)bi * CB + l + 64];

        // 2*logits >= g1-g0  <=>  pr^2*(w1+1e-20) >= (w0+1e-20); tie -> 1
        out[(size_t)bi * CB + l] =
            (pr0 * pr0 * (wv0.y + 1e-20) >= (wv0.x + 1e-20)) ? 1.0f : 0.0f;
        out[(size_t)bi * CB + l + 64] =
            (pr1 * pr1 * (wv1.y + 1e-20) >= (wv1.x + 1e-20)) ? 1.0f : 0.0f;
    }
}

// ---------------------------------------------------------------------------
extern "C" void kernel_launch(void* const* d_in, const int* in_sizes, int n_in,
                              void* d_out, int out_size, void* d_ws, size_t ws_size,
                              hipStream_t stream) {
    const float* x  = (const float*)d_in[0];   // (16,128,512)
    const float* A  = (const float*)d_in[1];   // (257,257)
    const float* gu = (const float*)d_in[2];   // (16,128,128,2)
    float* out = (float*)d_out;                // (16,1,128,128)

    char* base = (char*)d_ws;
    const size_t szAt  = (size_t)KF * NP * 8;        //   565,760
    const size_t szXft = (size_t)KF * NROW * 8;      // 4,259,840
    const size_t szZt  = (size_t)16 * NP * CB * 8;   // 4,456,448

    double*  At_d = (double*)base;
    double*  xft  = (double*)(base + szAt);
    double*  Zt   = (double*)(base + szAt + szXft);
    double2* w01  = (double2*)(base + szAt + szXft + szZt);  // 4,194,304

    hipLaunchKernelGGL(k_fftprep, dim3(3673), dim3(128), 0, stream,
                       x, A, gu, xft, At_d, w01);
    hipLaunchKernelGGL(k_zgm, dim3(16), dim3(1024), (size_t)CB * CB * 8, stream,
                       xft, At_d, Zt, w01, out);
}